// Round 1
// baseline (3979.090 us; speedup 1.0000x reference)
//
#include <hip/hip_runtime.h>
#include <math.h>

#define NN 50000
#define EE 800000
#define HH 128
#define FF 64
#define GG 8

__device__ __forceinline__ float sigm(float x){ return 1.0f/(1.0f+expf(-x)); }

// ---------- small setup: epigenetic scale + dt ----------
__global__ void k_setup(const float* __restrict__ meth,
                        const float* __restrict__ histones,
                        const float* __restrict__ logd,
                        float* __restrict__ scal)
{
    int l = threadIdx.x; // 64 threads = 1 wave
    float s = sigm(meth[l]) + sigm(meth[l + 64]);
#pragma unroll
    for (int o = 32; o >= 1; o >>= 1) s += __shfl_xor(s, o, 64);
    if (l == 0) {
        float msil = s * (1.0f / 128.0f);
        float h0 = sigm(histones[0]), h1 = sigm(histones[1]);
        float h2 = sigm(histones[2]), h3 = sigm(histones[3]);
        float act = (h0 + h2) * 0.5f, rep = (h1 + h3) * 0.5f;
        float chrom = fminf(fmaxf(act - rep + 0.5f, 0.0f), 1.0f);
        scal[0] = chrom * (1.0f - msil);
        float d = expf(logd[0]);
        scal[1] = fminf(fmaxf(d, 0.1f), 3.0f);   // dt
    }
}

// ---------- CSR build ----------
__global__ void k_hist(const int* __restrict__ ei, int* __restrict__ hist)
{
    int e = blockIdx.x * 256 + threadIdx.x;
    if (e < EE) atomicAdd(&hist[ei[EE + e]], 1);
}

__global__ void k_dinv(const int* __restrict__ hist, float* __restrict__ dinv)
{
    int n = blockIdx.x * 256 + threadIdx.x;
    if (n < NN) {
        int d = hist[n];
        dinv[n] = d > 0 ? rsqrtf((float)d) : 0.0f;
    }
}

// 3-phase exclusive scan of hist[NN] -> row_ptr[NN+1]
__global__ void k_scan_a(const int* __restrict__ hist, int* __restrict__ aux)
{
    __shared__ int sh[256];
    int b = blockIdx.x, t = threadIdx.x;
    int base = b * 1024 + t * 4;
    int s = 0;
#pragma unroll
    for (int j = 0; j < 4; ++j) { int i = base + j; if (i < NN) s += hist[i]; }
    sh[t] = s; __syncthreads();
    for (int o = 128; o >= 1; o >>= 1) { if (t < o) sh[t] += sh[t + o]; __syncthreads(); }
    if (t == 0) aux[b] = sh[0];
}

__global__ void k_scan_b(int* __restrict__ aux, int nb)
{
    if (blockIdx.x == 0 && threadIdx.x == 0) {
        int run = 0;
        for (int i = 0; i < nb; ++i) { int v = aux[i]; aux[i] = run; run += v; }
    }
}

__global__ void k_scan_c(const int* __restrict__ hist, const int* __restrict__ aux,
                         int* __restrict__ row_ptr)
{
    __shared__ int sh[256];
    int b = blockIdx.x, t = threadIdx.x;
    int base = b * 1024 + t * 4;
    int v[4]; int s = 0;
#pragma unroll
    for (int j = 0; j < 4; ++j) { int i = base + j; v[j] = (i < NN) ? hist[i] : 0; s += v[j]; }
    sh[t] = s; __syncthreads();
    for (int o = 1; o < 256; o <<= 1) {
        int x = 0; if (t >= o) x = sh[t - o];
        __syncthreads(); sh[t] += x; __syncthreads();
    }
    int run = aux[b] + sh[t] - s;  // exclusive prefix for this thread's chunk
#pragma unroll
    for (int j = 0; j < 4; ++j) { int i = base + j; if (i < NN) row_ptr[i] = run; run += v[j]; }
    if (b == 0 && t == 0) row_ptr[NN] = EE;
}

__global__ void k_scatter(const int* __restrict__ ei, const float* __restrict__ dinv,
                          int* __restrict__ cursor, int* __restrict__ srcs,
                          float* __restrict__ wgt)
{
    int e = blockIdx.x * 256 + threadIdx.x;
    if (e >= EE) return;
    int s = ei[e], d = ei[EE + e];
    int p = atomicAdd(&cursor[d], 1);
    srcs[p] = s;
    wgt[p]  = dinv[s] * dinv[d];
}

__global__ void k_cnt(const int* __restrict__ batch, int* __restrict__ cnt)
{
    int n = blockIdx.x * 256 + threadIdx.x;
    if (n < NN) atomicAdd(&cnt[batch[n]], 1);
}

// ---------- dense [N,K]@[K,128] + bias (+LN (+relu*scale)) ----------
// MODE 0: out = LN(A@W + b)            MODE 1: out = relu(LN(A@W+b)) * scal[0]
// block 256 = 4 waves; wave owns 4 rows; lane owns cols {2l,2l+1}; 128 rows/block.
template<int K, int MODE>
__global__ __launch_bounds__(256) void k_dense(
    const float* __restrict__ A, const float* __restrict__ W,
    const float* __restrict__ bias,
    const float* __restrict__ lng, const float* __restrict__ lnb,
    const float* __restrict__ scal, float* __restrict__ out)
{
    __shared__ float Ws[64 * 128];      // one 64-k half of W (32 KB)
    __shared__ float rb[16][K];         // staged rows
    const int t = threadIdx.x, wave = t >> 6, lane = t & 63;
    const int c0 = 2 * lane;
    const int wr0 = wave * 4;

    for (int it = 0; it < 8; ++it) {
        const int rbase = (blockIdx.x * 8 + it) * 16;
#pragma unroll
        for (int r = 0; r < 4; ++r) {
            int row = rbase + wr0 + r;
            if (K == 128) {
                float2 v = make_float2(0.f, 0.f);
                if (row < NN) v = ((const float2*)(A + (size_t)row * K))[lane];
                ((float2*)&rb[wr0 + r][0])[lane] = v;
            } else {
                float v = 0.f;
                if (row < NN) v = A[(size_t)row * K + lane];
                rb[wr0 + r][lane] = v;
            }
        }
        float acc[4][2] = {{0,0},{0,0},{0,0},{0,0}};
#pragma unroll
        for (int half = 0; half < K / 64; ++half) {
            __syncthreads();
            const float4* Wg = (const float4*)(W + half * 64 * 128);
#pragma unroll
            for (int i = 0; i < 8; ++i) ((float4*)Ws)[t + i * 256] = Wg[t + i * 256];
            __syncthreads();
#pragma unroll 8
            for (int k = 0; k < 64; ++k) {
                float2 wv = ((const float2*)&Ws[k * 128])[lane];
                int kk = half * 64 + k;
#pragma unroll
                for (int r = 0; r < 4; ++r) {
                    float a = rb[wr0 + r][kk];
                    acc[r][0] = fmaf(a, wv.x, acc[r][0]);
                    acc[r][1] = fmaf(a, wv.y, acc[r][1]);
                }
            }
        }
#pragma unroll
        for (int r = 0; r < 4; ++r) {
            int row = rbase + wr0 + r;
            if (row < NN) {   // wave-uniform branch
                float a0 = acc[r][0] + bias[c0];
                float a1 = acc[r][1] + bias[c0 + 1];
                float s = a0 + a1, q = a0 * a0 + a1 * a1;
#pragma unroll
                for (int o = 32; o >= 1; o >>= 1) {
                    s += __shfl_xor(s, o, 64);
                    q += __shfl_xor(q, o, 64);
                }
                float m  = s * (1.0f / 128.0f);
                float v  = q * (1.0f / 128.0f) - m * m;
                float rs = rsqrtf(v + 1e-5f);
                a0 = (a0 - m) * rs * lng[c0]     + lnb[c0];
                a1 = (a1 - m) * rs * lng[c0 + 1] + lnb[c0 + 1];
                if (MODE == 1) {
                    float sc = scal[0];
                    a0 = fmaxf(a0, 0.f) * sc;
                    a1 = fmaxf(a1, 0.f) * sc;
                }
                ((float2*)(out + (size_t)row * 128))[lane] = make_float2(a0, a1);
            }
        }
    }
}

// ---------- fused gate: g=sigmoid([cur,hnew]@GW+gb); cur = g*hnew+(1-g)*cur ----------
__global__ __launch_bounds__(256) void k_gate(
    float* __restrict__ cur, const float* __restrict__ hnew,
    const float* __restrict__ GW, const float* __restrict__ gb)
{
    __shared__ float Ws[64 * 128];
    __shared__ float rb[16][256];
    const int t = threadIdx.x, wave = t >> 6, lane = t & 63;
    const int c0 = 2 * lane;
    const int wr0 = wave * 4;

    for (int it = 0; it < 8; ++it) {
        const int rbase = (blockIdx.x * 8 + it) * 16;
#pragma unroll
        for (int r = 0; r < 4; ++r) {
            int row = rbase + wr0 + r;
            float2 v0 = make_float2(0.f, 0.f), v1 = make_float2(0.f, 0.f);
            if (row < NN) {
                v0 = ((const float2*)(cur  + (size_t)row * 128))[lane];
                v1 = ((const float2*)(hnew + (size_t)row * 128))[lane];
            }
            ((float2*)&rb[wr0 + r][0])[lane]   = v0;
            ((float2*)&rb[wr0 + r][128])[lane] = v1;
        }
        float acc[4][2] = {{0,0},{0,0},{0,0},{0,0}};
#pragma unroll
        for (int half = 0; half < 4; ++half) {
            __syncthreads();
            const float4* Wg = (const float4*)(GW + half * 64 * 128);
#pragma unroll
            for (int i = 0; i < 8; ++i) ((float4*)Ws)[t + i * 256] = Wg[t + i * 256];
            __syncthreads();
#pragma unroll 8
            for (int k = 0; k < 64; ++k) {
                float2 wv = ((const float2*)&Ws[k * 128])[lane];
                int kk = half * 64 + k;
#pragma unroll
                for (int r = 0; r < 4; ++r) {
                    float a = rb[wr0 + r][kk];
                    acc[r][0] = fmaf(a, wv.x, acc[r][0]);
                    acc[r][1] = fmaf(a, wv.y, acc[r][1]);
                }
            }
        }
#pragma unroll
        for (int r = 0; r < 4; ++r) {
            int row = rbase + wr0 + r;
            if (row < NN) {
                float g0 = sigm(acc[r][0] + gb[c0]);
                float g1 = sigm(acc[r][1] + gb[c0 + 1]);
                float cu0 = rb[wr0 + r][c0],       cu1 = rb[wr0 + r][c0 + 1];
                float hn0 = rb[wr0 + r][128 + c0], hn1 = rb[wr0 + r][128 + c0 + 1];
                ((float2*)(cur + (size_t)row * 128))[lane] =
                    make_float2(g0 * hn0 + (1.f - g0) * cu0,
                                g1 * hn1 + (1.f - g1) * cu1);
            }
        }
    }
}

// ---------- SpMM: out[n,:] = sum_e w[e] * X[src[e],:]  (wave per node) ----------
__global__ __launch_bounds__(256) void k_spmm(
    const int* __restrict__ row_ptr, const int* __restrict__ srcs,
    const float* __restrict__ wgt, const float* __restrict__ X,
    float* __restrict__ out)
{
    int node = (int)(blockIdx.x * 4 + (threadIdx.x >> 6));
    int lane = threadIdx.x & 63;
    if (node >= NN) return;
    int beg = row_ptr[node], end = row_ptr[node + 1];
    float2 acc = make_float2(0.f, 0.f);
    for (int e = beg; e < end; ++e) {
        int s = srcs[e]; float w = wgt[e];
        float2 v = ((const float2*)(X + (size_t)s * 128))[lane];
        acc.x = fmaf(w, v.x, acc.x);
        acc.y = fmaf(w, v.y, acc.y);
    }
    ((float2*)(out + (size_t)node * 128))[lane] = acc;
}

// ---------- RK4 stage combine: t=tanh(cur)+rw*fin; acc(+)=w*t; y=h0+c*t (or h0+acc) ----------
template<int S>
__global__ __launch_bounds__(256) void k_stage(
    const float* __restrict__ cur, const float* __restrict__ fin,
    const float* __restrict__ h0, float* __restrict__ acc,
    float* __restrict__ ybuf, const float* __restrict__ scal,
    const float* __restrict__ rwp)
{
    size_t i = (size_t)blockIdx.x * 256 + threadIdx.x;
    constexpr size_t TOT = (size_t)NN * 128 / 4;
    if (i >= TOT) return;
    float dt = scal[1], rw = rwp[0];
    float wk = (S == 1 || S == 4) ? dt * (1.f / 6.f) : dt * (1.f / 3.f);
    float4 c = ((const float4*)cur)[i];
    float4 f = ((const float4*)fin)[i];
    float4 h = ((const float4*)h0)[i];
    float4 tv;
    tv.x = tanhf(c.x) + rw * f.x;
    tv.y = tanhf(c.y) + rw * f.y;
    tv.z = tanhf(c.z) + rw * f.z;
    tv.w = tanhf(c.w) + rw * f.w;
    float4 a;
    if (S == 1) { a.x = wk*tv.x; a.y = wk*tv.y; a.z = wk*tv.z; a.w = wk*tv.w; }
    else {
        a = ((const float4*)acc)[i];
        a.x += wk*tv.x; a.y += wk*tv.y; a.z += wk*tv.z; a.w += wk*tv.w;
    }
    ((float4*)acc)[i] = a;
    float4 y;
    if (S == 4) { y.x = h.x + a.x; y.y = h.y + a.y; y.z = h.z + a.z; y.w = h.w + a.w; }
    else {
        float cn = (S == 3) ? dt : 0.5f * dt;
        y.x = h.x + cn*tv.x; y.y = h.y + cn*tv.y; y.z = h.z + cn*tv.z; y.w = h.w + cn*tv.w;
    }
    ((float4*)ybuf)[i] = y;
}

// ---------- pooling ----------
__global__ __launch_bounds__(128) void k_pool(
    const float* __restrict__ h, const int* __restrict__ batch,
    float* __restrict__ out)
{
    int c = threadIdx.x;                    // col 0..127
    int r0 = blockIdx.x * 512;
    int r1 = r0 + 512; if (r1 > NN) r1 = NN;
    if (r0 >= NN) return;
    float acc = 0.f; int g = batch[r0];
    for (int r = r0; r < r1; ++r) {
        int gg = batch[r];
        if (gg != g) { atomicAdd(&out[g * 128 + c], acc); acc = 0.f; g = gg; }
        acc += h[(size_t)r * 128 + c];
    }
    atomicAdd(&out[g * 128 + c], acc);
}

__global__ void k_div(float* __restrict__ out, const int* __restrict__ cnt)
{
    int i = blockIdx.x * 256 + threadIdx.x;
    if (i < GG * 128) {
        int c = cnt[i >> 7];
        out[i] = out[i] / (float)(c > 0 ? c : 1);
    }
}

// ---------- host ----------
static inline size_t al16(size_t x) { return (x + 15) & ~(size_t)15; }

extern "C" void kernel_launch(void* const* d_in, const int* in_sizes, int n_in,
                              void* d_out, int out_size, void* d_ws, size_t ws_size,
                              hipStream_t stream)
{
    const float* x       = (const float*)d_in[0];
    const int*   ei      = (const int*)d_in[1];
    const int*   batch   = (const int*)d_in[2];
    const float* in_w    = (const float*)d_in[3];
    const float* in_b    = (const float*)d_in[4];
    const float* in_lng  = (const float*)d_in[5];
    const float* in_lnb  = (const float*)d_in[6];
    const float* meth    = (const float*)d_in[7];
    const float* histn   = (const float*)d_in[8];
    const float* logd    = (const float*)d_in[9];
    const float* gcn_w   = (const float*)d_in[10];
    const float* gcn_b   = (const float*)d_in[11];
    const float* ln_g    = (const float*)d_in[12];
    const float* ln_b    = (const float*)d_in[13];
    const float* gate_w  = (const float*)d_in[14];
    const float* gate_b  = (const float*)d_in[15];
    const float* rw      = (const float*)d_in[16];
    const float* out_w   = (const float*)d_in[17];
    const float* out_b   = (const float*)d_in[18];
    const float* out_lng = (const float*)d_in[19];
    const float* out_lnb = (const float*)d_in[20];
    float* out = (float*)d_out;

    char* w = (char*)d_ws;
    size_t off = 0;
    float* scal   = (float*)(w + off); off += al16(16 * 4);
    int*   hist   = (int*)(w + off);   off += al16((size_t)NN * 4);
    int*   rp     = (int*)(w + off);   off += al16((size_t)(NN + 1) * 4);
    int*   cursor = (int*)(w + off);   off += al16((size_t)(NN + 1) * 4);
    int*   aux    = (int*)(w + off);   off += al16(64 * 4);
    int*   cnt    = (int*)(w + off);   off += al16(16 * 4);
    float* dinv   = (float*)(w + off); off += al16((size_t)NN * 4);
    int*   srcs   = (int*)(w + off);   off += al16((size_t)EE * 4);
    float* wgt    = (float*)(w + off); off += al16((size_t)EE * 4);
    size_t BUFSZ = (size_t)NN * 128 * 4;
    float* h0  = (float*)(w + off); off += BUFSZ;
    float* acc = (float*)(w + off); off += BUFSZ;
    float* y   = (float*)(w + off); off += BUFSZ;
    float* cur = (float*)(w + off); off += BUFSZ;
    float* t1  = (float*)(w + off); off += BUFSZ;
    float* t2  = (float*)(w + off); off += BUFSZ;
    if (off > ws_size) return;   // workspace too small: bail (will fail check loudly)

    hipMemsetAsync(hist, 0, (size_t)NN * 4, stream);
    hipMemsetAsync(cnt, 0, 16 * 4, stream);
    hipMemsetAsync(d_out, 0, (size_t)GG * 128 * 4, stream);

    k_setup<<<1, 64, 0, stream>>>(meth, histn, logd, scal);
    k_hist<<<(EE + 255) / 256, 256, 0, stream>>>(ei, hist);
    k_dinv<<<(NN + 255) / 256, 256, 0, stream>>>(hist, dinv);
    k_scan_a<<<49, 256, 0, stream>>>(hist, aux);
    k_scan_b<<<1, 1, 0, stream>>>(aux, 49);
    k_scan_c<<<49, 256, 0, stream>>>(hist, aux, rp);
    hipMemcpyAsync(cursor, rp, (size_t)(NN + 1) * 4, hipMemcpyDeviceToDevice, stream);
    k_scatter<<<(EE + 255) / 256, 256, 0, stream>>>(ei, dinv, cursor, srcs, wgt);
    k_cnt<<<(NN + 255) / 256, 256, 0, stream>>>(batch, cnt);

    const int DG = (NN + 127) / 128;   // dense grid: 391
    // input projection: h0 = relu(LN(x@in_w+in_b)) * scale
    k_dense<64, 1><<<DG, 256, 0, stream>>>(x, in_w, in_b, in_lng, in_lnb, scal, h0);

    for (int s = 1; s <= 4; ++s) {
        const float* fin = (s == 1) ? h0 : y;
        // layer 0
        k_spmm<<<12500, 256, 0, stream>>>(rp, srcs, wgt, fin, t1);
        k_dense<128, 0><<<DG, 256, 0, stream>>>(t1, gcn_w, gcn_b, ln_g, ln_b, scal, cur);
        // layers 1,2 with gating
        for (int i = 1; i <= 2; ++i) {
            k_spmm<<<12500, 256, 0, stream>>>(rp, srcs, wgt, cur, t1);
            k_dense<128, 0><<<DG, 256, 0, stream>>>(t1, gcn_w + (size_t)i * 128 * 128,
                                                    gcn_b + i * 128, ln_g + i * 128,
                                                    ln_b + i * 128, scal, t2);
            k_gate<<<DG, 256, 0, stream>>>(cur, t2, gate_w, gate_b);
        }
        if (s == 1)      k_stage<1><<<6250, 256, 0, stream>>>(cur, fin, h0, acc, y, scal, rw);
        else if (s == 2) k_stage<2><<<6250, 256, 0, stream>>>(cur, fin, h0, acc, y, scal, rw);
        else if (s == 3) k_stage<3><<<6250, 256, 0, stream>>>(cur, fin, h0, acc, y, scal, rw);
        else             k_stage<4><<<6250, 256, 0, stream>>>(cur, fin, h0, acc, y, scal, rw);
    }

    // output projection + pool
    k_dense<128, 0><<<DG, 256, 0, stream>>>(y, out_w, out_b, out_lng, out_lnb, scal, t2);
    k_pool<<<(NN + 511) / 512, 128, 0, stream>>>(t2, batch, out);
    k_div<<<4, 256, 0, stream>>>(out, cnt);
}

// Round 2
// 1618.597 us; speedup vs baseline: 2.4584x; 2.4584x over previous
//
#include <hip/hip_runtime.h>
#include <math.h>

#define NN 50000
#define EE 800000
#define HH 128
#define FF 64
#define GG 8

using short8 = __attribute__((ext_vector_type(8))) short;
using f32x4  = __attribute__((ext_vector_type(4))) float;

__device__ __forceinline__ float sigm(float x){ return 1.0f/(1.0f+expf(-x)); }
__device__ __forceinline__ unsigned short f2bf(float f){
    union { float f; unsigned u; } v; v.f = f;
    unsigned r = v.u + 0x7fff + ((v.u >> 16) & 1);
    return (unsigned short)(r >> 16);
}
__device__ __forceinline__ float bf2f(unsigned short h){
    union { unsigned u; float f; } v; v.u = ((unsigned)h) << 16;
    return v.f;
}

// ---------- small setup: epigenetic scale + dt ----------
__global__ void k_setup(const float* __restrict__ meth,
                        const float* __restrict__ histones,
                        const float* __restrict__ logd,
                        float* __restrict__ scal)
{
    int l = threadIdx.x;
    float s = sigm(meth[l]) + sigm(meth[l + 64]);
#pragma unroll
    for (int o = 32; o >= 1; o >>= 1) s += __shfl_xor(s, o, 64);
    if (l == 0) {
        float msil = s * (1.0f / 128.0f);
        float h0 = sigm(histones[0]), h1 = sigm(histones[1]);
        float h2 = sigm(histones[2]), h3 = sigm(histones[3]);
        float act = (h0 + h2) * 0.5f, rep = (h1 + h3) * 0.5f;
        float chrom = fminf(fmaxf(act - rep + 0.5f, 0.0f), 1.0f);
        scal[0] = chrom * (1.0f - msil);
        float d = expf(logd[0]);
        scal[1] = fminf(fmaxf(d, 0.1f), 3.0f);   // dt
    }
}

// ---------- weight pack: fp32 [K][128] -> bf16 B-fragment layout ----------
// dst[((c*8+b)*64 + lane)*8 + j] = W[c*32 + (lane>>4)*8 + j][b*16 + (lane&15)]
__global__ void k_pack(const float* __restrict__ W, unsigned short* __restrict__ out, int K)
{
    int i = blockIdx.x * 256 + threadIdx.x;
    if (i >= K * 128) return;
    int k = i >> 7, n = i & 127;
    int c = k >> 5, kl = k & 31, q = kl >> 3, j = kl & 7;
    int b = n >> 4, ln = n & 15;
    int lane = q * 16 + ln;
    out[((c * 8 + b) * 64 + lane) * 8 + j] = f2bf(W[i]);
}

// ---------- x fp32 -> bf16 ----------
__global__ void k_cvtx(const float* __restrict__ x, unsigned short* __restrict__ xb)
{
    size_t i = (size_t)blockIdx.x * 256 + threadIdx.x;
    if (i >= (size_t)NN * 16) return;
    float4 v = ((const float4*)x)[i];
    ushort4 o;
    o.x = f2bf(v.x); o.y = f2bf(v.y); o.z = f2bf(v.z); o.w = f2bf(v.w);
    ((ushort4*)xb)[i] = o;
}

// ---------- CSR build ----------
__global__ void k_hist(const int* __restrict__ ei, int* __restrict__ hist)
{
    int e = blockIdx.x * 256 + threadIdx.x;
    if (e < EE) atomicAdd(&hist[ei[EE + e]], 1);
}

__global__ void k_dinv(const int* __restrict__ hist, float* __restrict__ dinv)
{
    int n = blockIdx.x * 256 + threadIdx.x;
    if (n < NN) {
        int d = hist[n];
        dinv[n] = d > 0 ? rsqrtf((float)d) : 0.0f;
    }
}

__global__ void k_scan_a(const int* __restrict__ hist, int* __restrict__ aux)
{
    __shared__ int sh[256];
    int b = blockIdx.x, t = threadIdx.x;
    int base = b * 1024 + t * 4;
    int s = 0;
#pragma unroll
    for (int j = 0; j < 4; ++j) { int i = base + j; if (i < NN) s += hist[i]; }
    sh[t] = s; __syncthreads();
    for (int o = 128; o >= 1; o >>= 1) { if (t < o) sh[t] += sh[t + o]; __syncthreads(); }
    if (t == 0) aux[b] = sh[0];
}

__global__ void k_scan_b(int* __restrict__ aux, int nb)
{
    if (blockIdx.x == 0 && threadIdx.x == 0) {
        int run = 0;
        for (int i = 0; i < nb; ++i) { int v = aux[i]; aux[i] = run; run += v; }
    }
}

__global__ void k_scan_c(const int* __restrict__ hist, const int* __restrict__ aux,
                         int* __restrict__ row_ptr)
{
    __shared__ int sh[256];
    int b = blockIdx.x, t = threadIdx.x;
    int base = b * 1024 + t * 4;
    int v[4]; int s = 0;
#pragma unroll
    for (int j = 0; j < 4; ++j) { int i = base + j; v[j] = (i < NN) ? hist[i] : 0; s += v[j]; }
    sh[t] = s; __syncthreads();
    for (int o = 1; o < 256; o <<= 1) {
        int x = 0; if (t >= o) x = sh[t - o];
        __syncthreads(); sh[t] += x; __syncthreads();
    }
    int run = aux[b] + sh[t] - s;
#pragma unroll
    for (int j = 0; j < 4; ++j) { int i = base + j; if (i < NN) row_ptr[i] = run; run += v[j]; }
    if (b == 0 && t == 0) row_ptr[NN] = EE;
}

__global__ void k_scatter(const int* __restrict__ ei, const float* __restrict__ dinv,
                          int* __restrict__ cursor, int* __restrict__ srcs,
                          float* __restrict__ wgt)
{
    int e = blockIdx.x * 256 + threadIdx.x;
    if (e >= EE) return;
    int s = ei[e], d = ei[EE + e];
    int p = atomicAdd(&cursor[d], 1);
    srcs[p] = s;
    wgt[p]  = dinv[s] * dinv[d];
}

// ---------- graph bounds via binary search (batch is sorted) ----------
__global__ void k_bounds(const int* __restrict__ batch, int* __restrict__ st)
{
    int g = threadIdx.x;
    if (g > GG) return;
    int lo = 0, hi = NN;
    while (lo < hi) { int mid = (lo + hi) >> 1; if (batch[mid] < g) lo = mid + 1; else hi = mid; }
    st[g] = lo;
}

// ---------- MFMA dense: out = [relu(]LN(A@W+b)[)*scale], A bf16 [N,K], out bf16 [N,128] ----------
// block: 256 thr = 4 waves; wave computes 16 rows x 128 cols; 64 rows/block.
template<int KC, int MODE>   // KC = K/32; MODE 0: LN only, MODE 1: relu(LN)*scal[0]
__global__ __launch_bounds__(256) void k_dense_mfma(
    const unsigned short* __restrict__ A, const unsigned short* __restrict__ Wp,
    const float* __restrict__ bias, const float* __restrict__ lng,
    const float* __restrict__ lnb, const float* __restrict__ scal,
    unsigned short* __restrict__ out)
{
    __shared__ unsigned short Ws[KC * 4096];
    const int t = threadIdx.x;
    {
        const float4* src = (const float4*)Wp;
        float4* dst = (float4*)Ws;
#pragma unroll
        for (int i = 0; i < KC * 2; ++i) dst[t + i * 256] = src[t + i * 256];
    }
    __syncthreads();
    const int wave = t >> 6, lane = t & 63;
    const int quad = lane >> 4, ln = lane & 15;
    const int r0 = blockIdx.x * 64 + wave * 16;
    const int K = KC * 32;
    const int arow = r0 + ln;
    const bool av = arow < NN;

    f32x4 acc[8] = {};
#pragma unroll
    for (int c = 0; c < KC; ++c) {
        short8 a = {};
        if (av) a = *(const short8*)(A + (size_t)arow * K + c * 32 + quad * 8);
#pragma unroll
        for (int b = 0; b < 8; ++b) {
            short8 bb = *(const short8*)&Ws[((c * 8 + b) * 64 + lane) * 8];
            acc[b] = __builtin_amdgcn_mfma_f32_16x16x32_bf16(a, bb, acc[b], 0, 0, 0);
        }
    }

    float b_s[8], g_s[8], e_s[8];
#pragma unroll
    for (int b = 0; b < 8; ++b) {
        int col = b * 16 + ln;
        b_s[b] = bias[col]; g_s[b] = lng[col]; e_s[b] = lnb[col];
    }
    float sc = (MODE == 1) ? scal[0] : 0.0f;
#pragma unroll
    for (int i = 0; i < 4; ++i) {
        int row = r0 + quad * 4 + i;
        float v[8]; float s = 0.f, q = 0.f;
#pragma unroll
        for (int b = 0; b < 8; ++b) { float x = acc[b][i] + b_s[b]; v[b] = x; s += x; q += x * x; }
#pragma unroll
        for (int o = 1; o < 16; o <<= 1) { s += __shfl_xor(s, o, 64); q += __shfl_xor(q, o, 64); }
        float m  = s * (1.0f / 128.0f);
        float vr = q * (1.0f / 128.0f) - m * m;
        float rs = rsqrtf(vr + 1e-5f);
        if (row < NN) {
#pragma unroll
            for (int b = 0; b < 8; ++b) {
                float o2 = (v[b] - m) * rs * g_s[b] + e_s[b];
                if (MODE == 1) o2 = fmaxf(o2, 0.f) * sc;
                out[(size_t)row * 128 + b * 16 + ln] = f2bf(o2);
            }
        }
    }
}

// ---------- MFMA gate: g=sigmoid([cur,hnew]@GW+gb); cur = g*hnew+(1-g)*cur ----------
__global__ __launch_bounds__(256) void k_gate_mfma(
    unsigned short* __restrict__ cur, const unsigned short* __restrict__ hnew,
    const unsigned short* __restrict__ Wp, const float* __restrict__ gb)
{
    __shared__ unsigned short Ws[16384];
    const int t = threadIdx.x;
    const int wave = t >> 6, lane = t & 63;
    const int quad = lane >> 4, ln = lane & 15;
    const int r0 = blockIdx.x * 64 + wave * 16;
    const int arow = r0 + ln;
    const bool av = arow < NN;

    f32x4 acc[8] = {};
#pragma unroll
    for (int s = 0; s < 2; ++s) {
        __syncthreads();
        {
            const float4* src = (const float4*)(Wp + (size_t)s * 16384);
            float4* dst = (float4*)Ws;
#pragma unroll
            for (int i = 0; i < 8; ++i) dst[t + i * 256] = src[t + i * 256];
        }
        __syncthreads();
        const unsigned short* A = s ? hnew : cur;
#pragma unroll
        for (int c = 0; c < 4; ++c) {
            short8 a = {};
            if (av) a = *(const short8*)(A + (size_t)arow * 128 + c * 32 + quad * 8);
#pragma unroll
            for (int b = 0; b < 8; ++b) {
                short8 bb = *(const short8*)&Ws[((c * 8 + b) * 64 + lane) * 8];
                acc[b] = __builtin_amdgcn_mfma_f32_16x16x32_bf16(a, bb, acc[b], 0, 0, 0);
            }
        }
    }

    float gb_s[8];
#pragma unroll
    for (int b = 0; b < 8; ++b) gb_s[b] = gb[b * 16 + ln];
#pragma unroll
    for (int i = 0; i < 4; ++i) {
        int row = r0 + quad * 4 + i;
        if (row < NN) {
#pragma unroll
            for (int b = 0; b < 8; ++b) {
                size_t idx = (size_t)row * 128 + b * 16 + ln;
                float g  = sigm(acc[b][i] + gb_s[b]);
                float cu = bf2f(cur[idx]);
                float hn = bf2f(hnew[idx]);
                cur[idx] = f2bf(g * hn + (1.f - g) * cu);
            }
        }
    }
}

// ---------- SpMM (bf16): out[n,:] = sum_e w[e] * X[src[e],:], wave per node ----------
__global__ __launch_bounds__(256) void k_spmm(
    const int* __restrict__ row_ptr, const int* __restrict__ srcs,
    const float* __restrict__ wgt, const unsigned short* __restrict__ X,
    unsigned short* __restrict__ out)
{
    int node = (int)(blockIdx.x * 4 + (threadIdx.x >> 6));
    int lane = threadIdx.x & 63;
    if (node >= NN) return;
    int beg = row_ptr[node], end = row_ptr[node + 1];
    float2 acc = make_float2(0.f, 0.f);
    for (int e = beg; e < end; ++e) {
        int s = srcs[e]; float w = wgt[e];
        ushort2 v = ((const ushort2*)(X + (size_t)s * 128))[lane];
        acc.x = fmaf(w, bf2f(v.x), acc.x);
        acc.y = fmaf(w, bf2f(v.y), acc.y);
    }
    ushort2 o; o.x = f2bf(acc.x); o.y = f2bf(acc.y);
    ((ushort2*)(out + (size_t)node * 128))[lane] = o;
}

// ---------- RK4 stage combine (bf16 state, fp32 accumulator) ----------
template<int S>
__global__ __launch_bounds__(256) void k_stage(
    const unsigned short* __restrict__ cur, const unsigned short* __restrict__ fin,
    const unsigned short* __restrict__ h0, float* __restrict__ acc,
    unsigned short* __restrict__ ybuf, const float* __restrict__ scal,
    const float* __restrict__ rwp)
{
    size_t i = (size_t)blockIdx.x * 256 + threadIdx.x;
    if (i >= (size_t)NN * 32) return;
    float dt = scal[1], rw = rwp[0];
    float wk = (S == 1 || S == 4) ? dt * (1.f / 6.f) : dt * (1.f / 3.f);
    ushort4 c4 = ((const ushort4*)cur)[i];
    ushort4 f4 = ((const ushort4*)fin)[i];
    ushort4 h4 = ((const ushort4*)h0)[i];
    float tv[4];
    tv[0] = tanhf(bf2f(c4.x)) + rw * bf2f(f4.x);
    tv[1] = tanhf(bf2f(c4.y)) + rw * bf2f(f4.y);
    tv[2] = tanhf(bf2f(c4.z)) + rw * bf2f(f4.z);
    tv[3] = tanhf(bf2f(c4.w)) + rw * bf2f(f4.w);
    float4 a;
    if (S == 1) { a.x = wk*tv[0]; a.y = wk*tv[1]; a.z = wk*tv[2]; a.w = wk*tv[3]; }
    else {
        a = ((const float4*)acc)[i];
        a.x += wk*tv[0]; a.y += wk*tv[1]; a.z += wk*tv[2]; a.w += wk*tv[3];
    }
    ((float4*)acc)[i] = a;
    float h[4] = { bf2f(h4.x), bf2f(h4.y), bf2f(h4.z), bf2f(h4.w) };
    ushort4 y;
    if (S == 4) {
        y.x = f2bf(h[0] + a.x); y.y = f2bf(h[1] + a.y);
        y.z = f2bf(h[2] + a.z); y.w = f2bf(h[3] + a.w);
    } else {
        float cn = (S == 3) ? dt : 0.5f * dt;
        y.x = f2bf(h[0] + cn*tv[0]); y.y = f2bf(h[1] + cn*tv[1]);
        y.z = f2bf(h[2] + cn*tv[2]); y.w = f2bf(h[3] + cn*tv[3]);
    }
    ((ushort4*)ybuf)[i] = y;
}

// ---------- pooling ----------
__global__ __launch_bounds__(128) void k_pool(
    const unsigned short* __restrict__ h, const int* __restrict__ batch,
    float* __restrict__ out)
{
    int c = threadIdx.x;
    int r0 = blockIdx.x * 512;
    int r1 = r0 + 512; if (r1 > NN) r1 = NN;
    if (r0 >= NN) return;
    float acc = 0.f; int g = batch[r0];
    for (int r = r0; r < r1; ++r) {
        int gg = batch[r];
        if (gg != g) { atomicAdd(&out[g * 128 + c], acc); acc = 0.f; g = gg; }
        acc += bf2f(h[(size_t)r * 128 + c]);
    }
    atomicAdd(&out[g * 128 + c], acc);
}

__global__ void k_div(float* __restrict__ out, const int* __restrict__ st)
{
    int i = blockIdx.x * 256 + threadIdx.x;
    if (i < GG * 128) {
        int g = i >> 7;
        int c = st[g + 1] - st[g];
        out[i] = out[i] / (float)(c > 0 ? c : 1);
    }
}

// ---------- host ----------
static inline size_t al(size_t x) { return (x + 255) & ~(size_t)255; }

extern "C" void kernel_launch(void* const* d_in, const int* in_sizes, int n_in,
                              void* d_out, int out_size, void* d_ws, size_t ws_size,
                              hipStream_t stream)
{
    const float* x       = (const float*)d_in[0];
    const int*   ei      = (const int*)d_in[1];
    const int*   batch   = (const int*)d_in[2];
    const float* in_w    = (const float*)d_in[3];
    const float* in_b    = (const float*)d_in[4];
    const float* in_lng  = (const float*)d_in[5];
    const float* in_lnb  = (const float*)d_in[6];
    const float* meth    = (const float*)d_in[7];
    const float* histn   = (const float*)d_in[8];
    const float* logd    = (const float*)d_in[9];
    const float* gcn_w   = (const float*)d_in[10];
    const float* gcn_b   = (const float*)d_in[11];
    const float* ln_g    = (const float*)d_in[12];
    const float* ln_b    = (const float*)d_in[13];
    const float* gate_w  = (const float*)d_in[14];
    const float* gate_b  = (const float*)d_in[15];
    const float* rw      = (const float*)d_in[16];
    const float* out_w   = (const float*)d_in[17];
    const float* out_b   = (const float*)d_in[18];
    const float* out_lng = (const float*)d_in[19];
    const float* out_lnb = (const float*)d_in[20];
    float* out = (float*)d_out;

    char* w = (char*)d_ws;
    size_t off = 0;
    float* scal   = (float*)(w + off); off += al(16 * 4);
    int*   hist   = (int*)(w + off);   off += al((size_t)NN * 4);
    int*   rp     = (int*)(w + off);   off += al((size_t)(NN + 1) * 4);
    int*   cursor = (int*)(w + off);   off += al((size_t)(NN + 1) * 4);
    int*   aux    = (int*)(w + off);   off += al(64 * 4);
    int*   st     = (int*)(w + off);   off += al(16 * 4);
    float* dinv   = (float*)(w + off); off += al((size_t)NN * 4);
    int*   srcs   = (int*)(w + off);   off += al((size_t)EE * 4);
    float* wgt    = (float*)(w + off); off += al((size_t)EE * 4);
    // packed bf16 weights
    unsigned short* inwp  = (unsigned short*)(w + off); off += al(64 * 128 * 2);
    unsigned short* gcnwp = (unsigned short*)(w + off); off += al((size_t)3 * 128 * 128 * 2);
    unsigned short* gwp   = (unsigned short*)(w + off); off += al((size_t)2 * 128 * 128 * 2);
    unsigned short* owp   = (unsigned short*)(w + off); off += al(128 * 128 * 2);
    // bf16 activations
    size_t B16 = al((size_t)NN * 128 * 2);
    unsigned short* xb  = (unsigned short*)(w + off); off += al((size_t)NN * 64 * 2);
    unsigned short* h0  = (unsigned short*)(w + off); off += B16;
    unsigned short* y   = (unsigned short*)(w + off); off += B16;
    unsigned short* cur = (unsigned short*)(w + off); off += B16;
    unsigned short* t1  = (unsigned short*)(w + off); off += B16;
    unsigned short* t2  = (unsigned short*)(w + off); off += B16;
    float* acc = (float*)(w + off); off += al((size_t)NN * 128 * 4);
    if (off > ws_size) return;

    hipMemsetAsync(hist, 0, (size_t)NN * 4, stream);
    hipMemsetAsync(d_out, 0, (size_t)GG * 128 * 4, stream);

    // setup + weight packing + x conversion (independent)
    k_setup<<<1, 64, 0, stream>>>(meth, histn, logd, scal);
    k_pack<<<32, 256, 0, stream>>>(in_w, inwp, 64);
    for (int i = 0; i < 3; ++i)
        k_pack<<<64, 256, 0, stream>>>(gcn_w + (size_t)i * 128 * 128,
                                       gcnwp + (size_t)i * 128 * 128, 128);
    k_pack<<<64, 256, 0, stream>>>(gate_w, gwp, 128);
    k_pack<<<64, 256, 0, stream>>>(gate_w + 128 * 128, gwp + 128 * 128, 128);
    k_pack<<<64, 256, 0, stream>>>(out_w, owp, 128);
    k_cvtx<<<3125, 256, 0, stream>>>(x, xb);

    // CSR build
    k_hist<<<(EE + 255) / 256, 256, 0, stream>>>(ei, hist);
    k_dinv<<<(NN + 255) / 256, 256, 0, stream>>>(hist, dinv);
    k_scan_a<<<49, 256, 0, stream>>>(hist, aux);
    k_scan_b<<<1, 1, 0, stream>>>(aux, 49);
    k_scan_c<<<49, 256, 0, stream>>>(hist, aux, rp);
    hipMemcpyAsync(cursor, rp, (size_t)(NN + 1) * 4, hipMemcpyDeviceToDevice, stream);
    k_scatter<<<(EE + 255) / 256, 256, 0, stream>>>(ei, dinv, cursor, srcs, wgt);
    k_bounds<<<1, 16, 0, stream>>>(batch, st);

    const int DG = (NN + 63) / 64;   // 782 blocks
    // input projection: h0 = relu(LN(x@in_w+in_b)) * scale
    k_dense_mfma<2, 1><<<DG, 256, 0, stream>>>(xb, inwp, in_b, in_lng, in_lnb, scal, h0);

    for (int s = 1; s <= 4; ++s) {
        const unsigned short* fin = (s == 1) ? h0 : y;
        k_spmm<<<12500, 256, 0, stream>>>(rp, srcs, wgt, fin, t1);
        k_dense_mfma<4, 0><<<DG, 256, 0, stream>>>(t1, gcnwp, gcn_b, ln_g, ln_b, scal, cur);
        for (int i = 1; i <= 2; ++i) {
            k_spmm<<<12500, 256, 0, stream>>>(rp, srcs, wgt, cur, t1);
            k_dense_mfma<4, 0><<<DG, 256, 0, stream>>>(
                t1, gcnwp + (size_t)i * 128 * 128, gcn_b + i * 128,
                ln_g + i * 128, ln_b + i * 128, scal, t2);
            k_gate_mfma<<<DG, 256, 0, stream>>>(cur, t2, gwp, gate_b);
        }
        if (s == 1)      k_stage<1><<<6250, 256, 0, stream>>>(cur, fin, h0, acc, y, scal, rw);
        else if (s == 2) k_stage<2><<<6250, 256, 0, stream>>>(cur, fin, h0, acc, y, scal, rw);
        else if (s == 3) k_stage<3><<<6250, 256, 0, stream>>>(cur, fin, h0, acc, y, scal, rw);
        else             k_stage<4><<<6250, 256, 0, stream>>>(cur, fin, h0, acc, y, scal, rw);
    }

    // output projection + pool
    k_dense_mfma<4, 0><<<DG, 256, 0, stream>>>(y, owp, out_b, out_lng, out_lnb, scal, t2);
    k_pool<<<(NN + 511) / 512, 128, 0, stream>>>(t2, batch, out);
    k_div<<<4, 256, 0, stream>>>(out, st);
}